// Round 7
// baseline (398.153 us; speedup 1.0000x reference)
//
#include <hip/hip_runtime.h>
#include <hip/hip_bf16.h>

#define NNODES 10000
#define NEDGES 320000
#define ETOT   (NEDGES + NNODES)
#define NGRAPH 100
#define CH     250   // HEADS*OUT
#define HOUT   125
#define MPAD   10048 // 157 * 64
#define NTILE  157   // MPAD/64
#define KP0    352   // layer-0 K=336 padded
#define KP1    256   // layers 1-3 K=250 padded
#define HPAD   256   // hb16 row stride (bf16) -> 512B rows
#define ECAP   128   // bucket capacity per node
#define DCAPW  128   // per-wave LDS edge cache (== ECAP)

typedef __attribute__((ext_vector_type(8))) short bf16x8;
typedef __attribute__((ext_vector_type(4))) float f32x4;

static __device__ __forceinline__ float bflo(unsigned int u){
  union{ unsigned int i; float f; } v; v.i = u << 16; return v.f;
}
static __device__ __forceinline__ float bfhi(unsigned int u){
  union{ unsigned int i; float f; } v; v.i = u & 0xffff0000u; return v.f;
}
static __device__ __forceinline__ unsigned short f2bfbits(float f){
  __hip_bfloat16 b = __float2bfloat16(f);
  union{ __hip_bfloat16 b; unsigned short s; } v; v.b = b; return v.s;
}

struct Args {
  const float* x; const int* eidx; const int* batch;
  const float *W0,*W1,*W2,*W3;
  __hip_bfloat16 *Abf0, *Wt0, *Wt1, *Wt2, *Wt3;
  int *cursor; unsigned short* bucket; int *gstart;
};

// ---------------- pre: bucketed edge placement + gstart + xconv + wconv ----------------
__global__ void k_pre(Args a){
  int gtid = blockIdx.x * blockDim.x + threadIdx.x;
  int gstr = gridDim.x * blockDim.x;
  for (int e = gtid; e < ETOT; e += gstr){
    int dst, src;
    if (e < NEDGES){ src = a.eidx[e]; dst = a.eidx[NEDGES + e]; }
    else           { src = e - NEDGES; dst = src; }
    int pos = atomicAdd(&a.cursor[dst], 1);
    if (pos < ECAP) a.bucket[(size_t)dst * ECAP + pos] = (unsigned short)src;
  }
  for (int n = gtid; n < NNODES; n += gstr){
    int b1 = a.batch[n];
    int b0 = (n == 0) ? -1 : a.batch[n-1];
    for (int b = b0 + 1; b <= b1; ++b) a.gstart[b] = n;
    if (n == NNODES - 1){
      for (int b = b1 + 1; b <= NGRAPH; ++b) a.gstart[b] = NNODES;
    }
  }
  // xconv: float4 in (rows are 16B aligned: 336*4 = 84*16), ushort4 out
  for (int j = gtid; j < NNODES * 84; j += gstr){
    int r = j / 84, c4 = (j - r * 84) * 4;
    float4 v = *(const float4*)(a.x + (size_t)r * 336 + c4);
    ushort4 o;
    o.x = f2bfbits(v.x); o.y = f2bfbits(v.y); o.z = f2bfbits(v.z); o.w = f2bfbits(v.w);
    *(ushort4*)(a.Abf0 + (size_t)r * KP0 + c4) = o;
  }
  const int T0 = 16 * KP0 * 16;
  const int T1 = 16 * KP1 * 16;
  int tot = T0 + 3*T1;
  for (int i = gtid; i < tot; i += gstr){
    const float* W; __hip_bfloat16* Wt; int K, Kp, li;
    if (i < T0)             { W = a.W0; Wt = a.Wt0; K = 336; Kp = KP0; li = i; }
    else if (i < T0 +   T1) { W = a.W1; Wt = a.Wt1; K = CH;  Kp = KP1; li = i - T0; }
    else if (i < T0 + 2*T1) { W = a.W2; Wt = a.Wt2; K = CH;  Kp = KP1; li = i - T0 - T1; }
    else                    { W = a.W3; Wt = a.Wt3; K = CH;  Kp = KP1; li = i - T0 - 2*T1; }
    int KC = Kp >> 5;
    int nt = li / (Kp * 16);
    int rem = li % (Kp * 16);
    int k = rem / 16;
    int n = rem % 16;
    int col = nt * 16 + n;
    float v = (k < K && col < CH) ? W[(size_t)k * CH + col] : 0.f;
    Wt[(((size_t)nt * KC + (k >> 5)) * 16 + n) * 32 + (k & 31)] = __float2bfloat16(v);
  }
}

// ---------------- layer-0 MFMA GEMM + fused attention scores (atomics) ----------------
__global__ __launch_bounds__(256) void k_gemm(
    const __hip_bfloat16* __restrict__ A, const __hip_bfloat16* __restrict__ Wt,
    __hip_bfloat16* __restrict__ Cb, const float* __restrict__ asrc,
    const float* __restrict__ adst, float* __restrict__ esrc, float* __restrict__ edst,
    int Kp){
  int wv = threadIdx.x >> 6, lane = threadIdx.x & 63;
  int n16 = lane & 15, q = lane >> 4;
  int KC = Kp >> 5;
  int rowbase = blockIdx.x * 64 + wv * 16;
  int bn = blockIdx.y * 64;
  int nt0 = bn >> 4;
  const __hip_bfloat16* ap = A  + (size_t)(rowbase + n16) * Kp + q * 8;
  const __hip_bfloat16* bp = Wt + ((size_t)nt0 * KC * 16 + n16) * 32 + q * 8;
  f32x4 ac0 = {0.f,0.f,0.f,0.f}, ac1 = ac0, ac2 = ac0, ac3 = ac0;
  for (int kc = 0; kc < KC; ++kc){
    bf16x8 a  = *(const bf16x8*)(ap + (size_t)kc * 32);
    bf16x8 b0 = *(const bf16x8*)(bp + ((size_t)0 * KC + kc) * 512);
    bf16x8 b1 = *(const bf16x8*)(bp + ((size_t)1 * KC + kc) * 512);
    bf16x8 b2 = *(const bf16x8*)(bp + ((size_t)2 * KC + kc) * 512);
    bf16x8 b3 = *(const bf16x8*)(bp + ((size_t)3 * KC + kc) * 512);
    ac0 = __builtin_amdgcn_mfma_f32_16x16x32_bf16(a, b0, ac0, 0, 0, 0);
    ac1 = __builtin_amdgcn_mfma_f32_16x16x32_bf16(a, b1, ac1, 0, 0, 0);
    ac2 = __builtin_amdgcn_mfma_f32_16x16x32_bf16(a, b2, ac2, 0, 0, 0);
    ac3 = __builtin_amdgcn_mfma_f32_16x16x32_bf16(a, b3, ac3, 0, 0, 0);
  }
  float es0[4] = {}, es1[4] = {}, ed0a[4] = {}, ed1a[4] = {};
  #define SCORE_T(AC, T) { \
    int col = bn + (T)*16 + n16; \
    bool ok = col < CH; \
    float av = ok ? asrc[col] : 0.f; \
    float dv = ok ? adst[col] : 0.f; \
    bool hh = col >= HOUT; \
    float av0 = hh ? 0.f : av, av1 = hh ? av : 0.f; \
    float dv0 = hh ? 0.f : dv, dv1 = hh ? dv : 0.f; \
    _Pragma("unroll") \
    for (int r = 0; r < 4; ++r){ \
      es0[r] += AC[r]*av0; es1[r] += AC[r]*av1; \
      ed0a[r] += AC[r]*dv0; ed1a[r] += AC[r]*dv1; } }
  SCORE_T(ac0, 0) SCORE_T(ac1, 1) SCORE_T(ac2, 2) SCORE_T(ac3, 3)
  #undef SCORE_T
  #pragma unroll
  for (int off = 1; off < 16; off <<= 1){
    #pragma unroll
    for (int r = 0; r < 4; ++r){
      es0[r]  += __shfl_xor(es0[r],  off);
      es1[r]  += __shfl_xor(es1[r],  off);
      ed0a[r] += __shfl_xor(ed0a[r], off);
      ed1a[r] += __shfl_xor(ed1a[r], off);
    }
  }
  if (n16 == 0){
    #pragma unroll
    for (int r = 0; r < 4; ++r){
      int row = rowbase + q*4 + r;
      if (row < NNODES){
        atomicAdd(&esrc[row*2+0], es0[r]);
        atomicAdd(&esrc[row*2+1], es1[r]);
        atomicAdd(&edst[row*2+0], ed0a[r]);
        atomicAdd(&edst[row*2+1], ed1a[r]);
      }
    }
  }
  // zero-fill cols >= CH so gathers read clean zeros
  #pragma unroll
  for (int r = 0; r < 4; ++r){
    int row = rowbase + q * 4 + r;
    if (row >= NNODES) continue;
    int col = bn + n16;
    __hip_bfloat16* cb = Cb + (size_t)row * HPAD + col;
    cb[0]  = __float2bfloat16(col      < CH ? ac0[r] : 0.f);
    cb[16] = __float2bfloat16(col + 16 < CH ? ac1[r] : 0.f);
    cb[32] = __float2bfloat16(col + 32 < CH ? ac2[r] : 0.f);
    cb[48] = __float2bfloat16(col + 48 < CH ? ac3[r] : 0.f);
  }
}

// ---------------- XCD-local sliced softmax+gather -------------------------------------
// Block = (node-group, 32-col slice).  slice = blockIdx&7: with round-robin block->XCD
// dispatch, all blocks of slice s land on XCD s -> per-XCD hot set = 10000 x 64B =
// 640KB < 4MB L2.  Each edge-read is exactly ONE 64B cacheline (16 lanes x 4B).
// Softmax denominator recomputed per slice (8x redundant exp ~ 0.5us total, trivial).
__global__ __launch_bounds__(256, 8) void k_gather(
    const __hip_bfloat16* __restrict__ h,
    const float* __restrict__ esrc, const float* __restrict__ edst,
    const int* __restrict__ degv, const unsigned short* __restrict__ bucket,
    const float* __restrict__ bias, __hip_bfloat16* __restrict__ outb){
  int wv = threadIdx.x >> 6, lane = threadIdx.x & 63;
  int s = blockIdx.x & 7;                    // col slice (XCD-local by round-robin)
  int node = (blockIdx.x >> 3) * 4 + wv;     // 2500 groups * 4 waves
  __shared__ unsigned short s_src[4][DCAPW];
  __shared__ float2 s_x[4][DCAPW];
  int deg = degv[node]; if (deg > ECAP) deg = ECAP;
  const unsigned short* __restrict__ eb = bucket + (size_t)node * ECAP;
  float ed0 = edst[node*2+0], ed1 = edst[node*2+1];
  // phase A: denominators + LDS edge cache (wave-private, no block sync needed)
  float sm0 = 0.f, sm1 = 0.f;
  for (int i = lane; i < deg; i += 64){
    int src = eb[i];
    float2 ev = *(const float2*)(esrc + (size_t)src * 2);
    float e0 = ev.x + ed0; e0 = e0 > 0.f ? e0 : 0.2f*e0;
    float e1 = ev.y + ed1; e1 = e1 > 0.f ? e1 : 0.2f*e1;
    float x0 = __expf(e0), x1 = __expf(e1);
    s_src[wv][i] = (unsigned short)src; s_x[wv][i] = make_float2(x0, x1);
    sm0 += x0; sm1 += x1;
  }
  #pragma unroll
  for (int off = 32; off > 0; off >>= 1){
    sm0 += __shfl_xor(sm0, off);
    sm1 += __shfl_xor(sm1, off);
  }
  float inv0 = 1.f / (sm0 + 1e-16f);
  float inv1 = 1.f / (sm1 + 1e-16f);
  // phase B: quarter-wave per edge, lane owns 2 cols (4B) of the 64B slice
  int quarter = lane >> 4, ql = lane & 15;
  int cL = s * 32 + ql * 2;
  bool selL = cL < HOUT, selH = (cL + 1) < HOUT;
  const __hip_bfloat16* __restrict__ hq = h + cL;
  float accL = 0.f, accH = 0.f;
  for (int it = quarter; it < deg; it += 16){   // 4 edges/wave/step, 4 loads in flight
    unsigned int dv[4]; float aL[4], aH[4];
    #pragma unroll
    for (int u = 0; u < 4; ++u){
      int ii = it + 4*u;
      bool vld = ii < deg;
      int jj = vld ? ii : 0;
      int sr = s_src[wv][jj];
      float2 xv = s_x[wv][jj];
      float x0 = vld ? xv.x : 0.f, x1 = vld ? xv.y : 0.f;
      aL[u] = selL ? x0 : x1;
      aH[u] = selH ? x0 : x1;
      dv[u] = *(const unsigned int*)(hq + (size_t)sr * HPAD);
    }
    #pragma unroll
    for (int u = 0; u < 4; ++u){
      accL += aL[u] * bflo(dv[u]);
      accH += aH[u] * bfhi(dv[u]);
    }
  }
  accL += __shfl_xor(accL, 16); accL += __shfl_xor(accL, 32);
  accH += __shfl_xor(accH, 16); accH += __shfl_xor(accH, 32);
  if (lane < 16){
    float vL = 0.f, vH = 0.f;
    if (cL < CH){
      vL = accL * (selL ? inv0 : inv1) + bias[cL];
      vL = vL > 0.f ? vL : 0.f;
    }
    if (cL + 1 < CH){
      vH = accH * (selH ? inv0 : inv1) + bias[cL + 1];
      vH = vH > 0.f ? vH : 0.f;
    }
    *(unsigned int*)(outb + (size_t)node * HPAD + cL) =
        (unsigned int)f2bfbits(vL) | ((unsigned int)f2bfbits(vH) << 16);
  }
}

// ---------------- layers 1-3 GEMM + next-layer scores (plain stores) -------------------
// Block = 16 nodes x 16 waves; wave w owns col-tile w. A from global (just-written
// gather output, L2/L3-resident). Full row per block -> no atomics, no zero-init.
__global__ __launch_bounds__(1024, 8) void k_gemm2(
    const __hip_bfloat16* __restrict__ A, const __hip_bfloat16* __restrict__ Wt,
    const float* __restrict__ asrc, const float* __restrict__ adst,
    __hip_bfloat16* __restrict__ hnext,
    float* __restrict__ esN, float* __restrict__ edN){
  int w = threadIdx.x >> 6, lane = threadIdx.x & 63;
  int nodebase = blockIdx.x * 16;               // 625 * 16 == NNODES
  __shared__ float esp[16][16][2];
  __shared__ float edp[16][16][2];
  int n16 = lane & 15, q = lane >> 4;
  const int KC = KP1 >> 5;                      // 8
  const __hip_bfloat16* bp = Wt + ((size_t)w * KC * 16 + n16) * 32 + q * 8;
  const __hip_bfloat16* ap = A + (size_t)(nodebase + n16) * KP1 + q * 8;
  f32x4 ac = {0.f,0.f,0.f,0.f};
  #pragma unroll
  for (int kc = 0; kc < KC; ++kc){
    bf16x8 av = *(const bf16x8*)(ap + (size_t)kc * 32);
    bf16x8 bv = *(const bf16x8*)(bp + (size_t)kc * 512);
    ac = __builtin_amdgcn_mfma_f32_16x16x32_bf16(av, bv, ac, 0, 0, 0);
  }
  int col = w * 16 + n16;
  bool ok = col < CH;
  float av_ = ok ? asrc[col] : 0.f;
  float dv_ = ok ? adst[col] : 0.f;
  bool hh = col >= HOUT;
  float av0 = hh ? 0.f : av_, av1 = hh ? av_ : 0.f;
  float dv0 = hh ? 0.f : dv_, dv1 = hh ? dv_ : 0.f;
  float es0[4], es1[4], edd0[4], edd1[4];
  #pragma unroll
  for (int r = 0; r < 4; ++r){
    es0[r] = ac[r]*av0; es1[r] = ac[r]*av1;
    edd0[r] = ac[r]*dv0; edd1[r] = ac[r]*dv1;
  }
  #pragma unroll
  for (int off = 1; off < 16; off <<= 1){
    #pragma unroll
    for (int r = 0; r < 4; ++r){
      es0[r]  += __shfl_xor(es0[r],  off);
      es1[r]  += __shfl_xor(es1[r],  off);
      edd0[r] += __shfl_xor(edd0[r], off);
      edd1[r] += __shfl_xor(edd1[r], off);
    }
  }
  if (n16 == 0){
    #pragma unroll
    for (int r = 0; r < 4; ++r){
      esp[w][q*4+r][0] = es0[r];  esp[w][q*4+r][1] = es1[r];
      edp[w][q*4+r][0] = edd0[r]; edp[w][q*4+r][1] = edd1[r];
    }
  }
  // hnext write: zero-fill cols >= CH for next gather
  #pragma unroll
  for (int r = 0; r < 4; ++r){
    int row = nodebase + q*4 + r;
    hnext[(size_t)row * HPAD + col] = __float2bfloat16(ok ? ac[r] : 0.f);
  }
  __syncthreads();
  int t = threadIdx.x;
  if (t < 64){
    int row = t >> 2;
    int he = t & 1;
    int which = (t >> 1) & 1;
    float sum = 0.f;
    #pragma unroll
    for (int w2 = 0; w2 < 16; ++w2)
      sum += which ? edp[w2][row][he] : esp[w2][row][he];
    (which ? edN : esN)[(size_t)(nodebase + row) * 2 + he] = sum;
  }
}

// ---------------- fused head: segmented mean pool (bf16 input) + 4-layer MLP -----------
__global__ __launch_bounds__(256) void k_head(const __hip_bfloat16* __restrict__ xb,
                        const int* __restrict__ gstart,
                        const float* __restrict__ lw1, const float* __restrict__ lb1,
                        const float* __restrict__ lw2, const float* __restrict__ lb2,
                        const float* __restrict__ lw3, const float* __restrict__ lb3,
                        const float* __restrict__ lw4, const float* __restrict__ lb4,
                        float* __restrict__ out){
  int g = blockIdx.x;
  int tid = threadIdx.x;
  int s = gstart[g], e = gstart[g+1];
  __shared__ float gvec[256];
  __shared__ float m1[200];
  __shared__ float m2[112];
  __shared__ float m3[112];
  if (tid < 128){
    int c2 = tid * 2;
    const __hip_bfloat16* xp = xb + c2;
    float a0=0.f,a1=0.f,b0=0.f,b1=0.f;
    int n = s;
    for (; n + 3 < e; n += 4){
      unsigned int u0 = *(const unsigned int*)(xp + (size_t)n     * KP1);
      unsigned int u1 = *(const unsigned int*)(xp + (size_t)(n+1) * KP1);
      unsigned int u2 = *(const unsigned int*)(xp + (size_t)(n+2) * KP1);
      unsigned int u3 = *(const unsigned int*)(xp + (size_t)(n+3) * KP1);
      a0 += bflo(u0) + bflo(u2); a1 += bfhi(u0) + bfhi(u2);
      b0 += bflo(u1) + bflo(u3); b1 += bfhi(u1) + bfhi(u3);
    }
    for (; n < e; ++n){
      unsigned int u0 = *(const unsigned int*)(xp + (size_t)n * KP1);
      a0 += bflo(u0); a1 += bfhi(u0);
    }
    float scale = 1.f / fmaxf((float)(e - s), 1.f);
    gvec[c2]     = (a0 + b0) * scale;
    gvec[c2 + 1] = (a1 + b1) * scale;
  }
  __syncthreads();
  if (tid < 200){
    float a0=0.f,a1=0.f,a2=0.f,a3=0.f;
    int k = 0;
    for (; k + 3 < CH; k += 4){
      a0 += gvec[k]   * lw1[(size_t)k     * 200 + tid];
      a1 += gvec[k+1] * lw1[(size_t)(k+1) * 200 + tid];
      a2 += gvec[k+2] * lw1[(size_t)(k+2) * 200 + tid];
      a3 += gvec[k+3] * lw1[(size_t)(k+3) * 200 + tid];
    }
    for (; k < CH; ++k) a0 += gvec[k] * lw1[(size_t)k * 200 + tid];
    float v = a0 + a1 + a2 + a3 + lb1[tid];
    m1[tid] = v > 0.f ? v : 0.f;
  }
  __syncthreads();
  if (tid < 100){
    float a0=0.f,a1=0.f,a2=0.f,a3=0.f;
    for (int k = 0; k + 3 < 200; k += 4){
      a0 += m1[k]   * lw2[(size_t)k     * 100 + tid];
      a1 += m1[k+1] * lw2[(size_t)(k+1) * 100 + tid];
      a2 += m1[k+2] * lw2[(size_t)(k+2) * 100 + tid];
      a3 += m1[k+3] * lw2[(size_t)(k+3) * 100 + tid];
    }
    float v = a0 + a1 + a2 + a3 + lb2[tid];
    m2[tid] = v > 0.f ? v : 0.f;
  }
  __syncthreads();
  if (tid < 100){
    float a0=0.f,a1=0.f,a2=0.f,a3=0.f;
    for (int k = 0; k + 3 < 100; k += 4){
      a0 += m2[k]   * lw3[(size_t)k     * 100 + tid];
      a1 += m2[k+1] * lw3[(size_t)(k+1) * 100 + tid];
      a2 += m2[k+2] * lw3[(size_t)(k+2) * 100 + tid];
      a3 += m2[k+3] * lw3[(size_t)(k+3) * 100 + tid];
    }
    float v = a0 + a1 + a2 + a3 + lb3[tid];
    m3[tid] = v > 0.f ? v : 0.f;
  }
  __syncthreads();
  if (tid < 29){
    float a0=0.f,a1=0.f,a2=0.f,a3=0.f;
    for (int k = 0; k + 3 < 100; k += 4){
      a0 += m3[k]   * lw4[(size_t)k     * 29 + tid];
      a1 += m3[k+1] * lw4[(size_t)(k+1) * 29 + tid];
      a2 += m3[k+2] * lw4[(size_t)(k+2) * 29 + tid];
      a3 += m3[k+3] * lw4[(size_t)(k+3) * 29 + tid];
    }
    out[(size_t)g * 29 + tid] = a0 + a1 + a2 + a3 + lb4[tid];
  }
}

// ---------------- launch ----------------
extern "C" void kernel_launch(void* const* d_in, const int* in_sizes, int n_in,
                              void* d_out, int out_size, void* d_ws, size_t ws_size,
                              hipStream_t stream){
  char* ws = (char*)d_ws;
  size_t off = 0;
  auto alloc = [&](size_t bytes)->void*{
    void* p = ws + off;
    off = (off + bytes + 255) & ~(size_t)255;
    return p;
  };
  __hip_bfloat16* hb16A = (__hip_bfloat16*)alloc((size_t)NNODES * HPAD * 2);
  __hip_bfloat16* hb16B = (__hip_bfloat16*)alloc((size_t)NNODES * HPAD * 2);
  __hip_bfloat16* Abf0 = (__hip_bfloat16*)alloc((size_t)MPAD * KP0 * 2);
  __hip_bfloat16* Abf  = (__hip_bfloat16*)alloc((size_t)MPAD * KP1 * 2);  // gather out
  __hip_bfloat16* Wt0  = (__hip_bfloat16*)alloc((size_t)16 * KP0 * 16 * 2);
  __hip_bfloat16* Wt1  = (__hip_bfloat16*)alloc((size_t)16 * KP1 * 16 * 2);
  __hip_bfloat16* Wt2  = (__hip_bfloat16*)alloc((size_t)16 * KP1 * 16 * 2);
  __hip_bfloat16* Wt3  = (__hip_bfloat16*)alloc((size_t)16 * KP1 * 16 * 2);
  size_t zbeg = off;
  int*   cursor = (int*)  alloc((size_t)NNODES * 4);      // doubles as deg
  float* esA  = (float*)alloc((size_t)NNODES * 2 * 4);    // layer-0 scores (atomics)
  float* edA  = (float*)alloc((size_t)NNODES * 2 * 4);
  size_t zend = off;
  float* esB  = (float*)alloc((size_t)NNODES * 2 * 4);    // plain-store targets
  float* edB  = (float*)alloc((size_t)NNODES * 2 * 4);
  unsigned short* bucket = (unsigned short*)alloc((size_t)NNODES * ECAP * 2);
  int*   gstart = (int*)alloc((size_t)(NGRAPH + 1) * 4);

  hipMemsetAsync(ws + zbeg, 0, zend - zbeg, stream);

  Args a;
  a.x = (const float*)d_in[0];
  a.eidx = (const int*)d_in[1];
  a.batch = (const int*)d_in[2];
  a.W0 = (const float*)d_in[3];  a.W1 = (const float*)d_in[7];
  a.W2 = (const float*)d_in[11]; a.W3 = (const float*)d_in[15];
  a.Abf0 = Abf0;
  a.Wt0 = Wt0; a.Wt1 = Wt1; a.Wt2 = Wt2; a.Wt3 = Wt3;
  a.cursor = cursor; a.bucket = bucket; a.gstart = gstart;

  k_pre<<<(ETOT + 255)/256, 256, 0, stream>>>(a);

  k_gemm<<<dim3(NTILE, 4), 256, 0, stream>>>(Abf0, Wt0, hb16A,
      (const float*)d_in[4], (const float*)d_in[5], esA, edA, KP0);

  const int GG = (NNODES/4) * 8;   // 20000 blocks, %8==0 -> clean XCD round-robin

  // L=1
  k_gather<<<GG, 256, 0, stream>>>(hb16A, esA, edA, cursor, bucket,
      (const float*)d_in[6], Abf);
  k_gemm2<<<NNODES/16, 1024, 0, stream>>>(Abf, Wt1,
      (const float*)d_in[8], (const float*)d_in[9], hb16B, esB, edB);
  // L=2
  k_gather<<<GG, 256, 0, stream>>>(hb16B, esB, edB, cursor, bucket,
      (const float*)d_in[10], Abf);
  k_gemm2<<<NNODES/16, 1024, 0, stream>>>(Abf, Wt2,
      (const float*)d_in[12], (const float*)d_in[13], hb16A, esA, edA);
  // L=3
  k_gather<<<GG, 256, 0, stream>>>(hb16A, esA, edA, cursor, bucket,
      (const float*)d_in[14], Abf);
  k_gemm2<<<NNODES/16, 1024, 0, stream>>>(Abf, Wt3,
      (const float*)d_in[16], (const float*)d_in[17], hb16B, esB, edB);
  // final attn -> head input
  k_gather<<<GG, 256, 0, stream>>>(hb16B, esB, edB, cursor, bucket,
      (const float*)d_in[18], Abf);

  k_head<<<NGRAPH, 256, 0, stream>>>(Abf, gstart,
      (const float*)d_in[19], (const float*)d_in[20],
      (const float*)d_in[21], (const float*)d_in[22],
      (const float*)d_in[23], (const float*)d_in[24],
      (const float*)d_in[25], (const float*)d_in[26],
      (float*)d_out);
}

// Round 8
// 292.472 us; speedup vs baseline: 1.3613x; 1.3613x over previous
//
#include <hip/hip_runtime.h>
#include <hip/hip_bf16.h>

#define NNODES 10000
#define NEDGES 320000
#define ETOT   (NEDGES + NNODES)
#define NGRAPH 100
#define CH     250   // HEADS*OUT
#define HOUT   125
#define MPAD   10048 // 157 * 64
#define NTILE  157   // MPAD/64
#define KP0    352   // layer-0 K=336 padded
#define KP1    256   // layers 1-3 K=250 padded
#define HPAD   256   // hb16 row stride (bf16) -> 512B rows
#define ECAP   128   // bucket capacity per node
#define DCAPW  128   // per-wave LDS edge cache (== ECAP)
#define APAD   264   // LDS A-tile row stride (shorts)

typedef __attribute__((ext_vector_type(8))) short bf16x8;
typedef __attribute__((ext_vector_type(4))) float f32x4;

static __device__ __forceinline__ float bflo(unsigned int u){
  union{ unsigned int i; float f; } v; v.i = u << 16; return v.f;
}
static __device__ __forceinline__ float bfhi(unsigned int u){
  union{ unsigned int i; float f; } v; v.i = u & 0xffff0000u; return v.f;
}
static __device__ __forceinline__ unsigned short f2bfbits(float f){
  __hip_bfloat16 b = __float2bfloat16(f);
  union{ __hip_bfloat16 b; unsigned short s; } v; v.b = b; return v.s;
}

struct Args {
  const float* x; const int* eidx; const int* batch;
  const float *W0,*W1,*W2,*W3;
  __hip_bfloat16 *Abf0, *Wt0, *Wt1, *Wt2, *Wt3;
  int *cursor; unsigned short* bucket; int *gstart;
};

// ---------------- pre: bucketed edge placement + gstart + xconv + wconv ----------------
__global__ void k_pre(Args a){
  int gtid = blockIdx.x * blockDim.x + threadIdx.x;
  int gstr = gridDim.x * blockDim.x;
  for (int e = gtid; e < ETOT; e += gstr){
    int dst, src;
    if (e < NEDGES){ src = a.eidx[e]; dst = a.eidx[NEDGES + e]; }
    else           { src = e - NEDGES; dst = src; }
    int pos = atomicAdd(&a.cursor[dst], 1);
    if (pos < ECAP) a.bucket[(size_t)dst * ECAP + pos] = (unsigned short)src;
  }
  for (int n = gtid; n < NNODES; n += gstr){
    int b1 = a.batch[n];
    int b0 = (n == 0) ? -1 : a.batch[n-1];
    for (int b = b0 + 1; b <= b1; ++b) a.gstart[b] = n;
    if (n == NNODES - 1){
      for (int b = b1 + 1; b <= NGRAPH; ++b) a.gstart[b] = NNODES;
    }
  }
  // xconv: float4 in (rows are 16B aligned: 336*4 = 84*16), ushort4 out
  for (int j = gtid; j < NNODES * 84; j += gstr){
    int r = j / 84, c4 = (j - r * 84) * 4;
    float4 v = *(const float4*)(a.x + (size_t)r * 336 + c4);
    ushort4 o;
    o.x = f2bfbits(v.x); o.y = f2bfbits(v.y); o.z = f2bfbits(v.z); o.w = f2bfbits(v.w);
    *(ushort4*)(a.Abf0 + (size_t)r * KP0 + c4) = o;
  }
  const int T0 = 16 * KP0 * 16;
  const int T1 = 16 * KP1 * 16;
  int tot = T0 + 3*T1;
  for (int i = gtid; i < tot; i += gstr){
    const float* W; __hip_bfloat16* Wt; int K, Kp, li;
    if (i < T0)             { W = a.W0; Wt = a.Wt0; K = 336; Kp = KP0; li = i; }
    else if (i < T0 +   T1) { W = a.W1; Wt = a.Wt1; K = CH;  Kp = KP1; li = i - T0; }
    else if (i < T0 + 2*T1) { W = a.W2; Wt = a.Wt2; K = CH;  Kp = KP1; li = i - T0 - T1; }
    else                    { W = a.W3; Wt = a.Wt3; K = CH;  Kp = KP1; li = i - T0 - 2*T1; }
    int KC = Kp >> 5;
    int nt = li / (Kp * 16);
    int rem = li % (Kp * 16);
    int k = rem / 16;
    int n = rem % 16;
    int col = nt * 16 + n;
    float v = (k < K && col < CH) ? W[(size_t)k * CH + col] : 0.f;
    Wt[(((size_t)nt * KC + (k >> 5)) * 16 + n) * 32 + (k & 31)] = __float2bfloat16(v);
  }
}

// ---------------- layer-0 MFMA GEMM + fused attention scores (atomics) ----------------
__global__ __launch_bounds__(256) void k_gemm(
    const __hip_bfloat16* __restrict__ A, const __hip_bfloat16* __restrict__ Wt,
    __hip_bfloat16* __restrict__ Cb, const float* __restrict__ asrc,
    const float* __restrict__ adst, float* __restrict__ esrc, float* __restrict__ edst,
    int Kp){
  int wv = threadIdx.x >> 6, lane = threadIdx.x & 63;
  int n16 = lane & 15, q = lane >> 4;
  int KC = Kp >> 5;
  int rowbase = blockIdx.x * 64 + wv * 16;
  int bn = blockIdx.y * 64;
  int nt0 = bn >> 4;
  const __hip_bfloat16* ap = A  + (size_t)(rowbase + n16) * Kp + q * 8;
  const __hip_bfloat16* bp = Wt + ((size_t)nt0 * KC * 16 + n16) * 32 + q * 8;
  f32x4 ac0 = {0.f,0.f,0.f,0.f}, ac1 = ac0, ac2 = ac0, ac3 = ac0;
  for (int kc = 0; kc < KC; ++kc){
    bf16x8 a  = *(const bf16x8*)(ap + (size_t)kc * 32);
    bf16x8 b0 = *(const bf16x8*)(bp + ((size_t)0 * KC + kc) * 512);
    bf16x8 b1 = *(const bf16x8*)(bp + ((size_t)1 * KC + kc) * 512);
    bf16x8 b2 = *(const bf16x8*)(bp + ((size_t)2 * KC + kc) * 512);
    bf16x8 b3 = *(const bf16x8*)(bp + ((size_t)3 * KC + kc) * 512);
    ac0 = __builtin_amdgcn_mfma_f32_16x16x32_bf16(a, b0, ac0, 0, 0, 0);
    ac1 = __builtin_amdgcn_mfma_f32_16x16x32_bf16(a, b1, ac1, 0, 0, 0);
    ac2 = __builtin_amdgcn_mfma_f32_16x16x32_bf16(a, b2, ac2, 0, 0, 0);
    ac3 = __builtin_amdgcn_mfma_f32_16x16x32_bf16(a, b3, ac3, 0, 0, 0);
  }
  float es0[4] = {}, es1[4] = {}, ed0a[4] = {}, ed1a[4] = {};
  #define SCORE_T(AC, T) { \
    int col = bn + (T)*16 + n16; \
    bool ok = col < CH; \
    float av = ok ? asrc[col] : 0.f; \
    float dv = ok ? adst[col] : 0.f; \
    bool hh = col >= HOUT; \
    float av0 = hh ? 0.f : av, av1 = hh ? av : 0.f; \
    float dv0 = hh ? 0.f : dv, dv1 = hh ? dv : 0.f; \
    _Pragma("unroll") \
    for (int r = 0; r < 4; ++r){ \
      es0[r] += AC[r]*av0; es1[r] += AC[r]*av1; \
      ed0a[r] += AC[r]*dv0; ed1a[r] += AC[r]*dv1; } }
  SCORE_T(ac0, 0) SCORE_T(ac1, 1) SCORE_T(ac2, 2) SCORE_T(ac3, 3)
  #undef SCORE_T
  #pragma unroll
  for (int off = 1; off < 16; off <<= 1){
    #pragma unroll
    for (int r = 0; r < 4; ++r){
      es0[r]  += __shfl_xor(es0[r],  off);
      es1[r]  += __shfl_xor(es1[r],  off);
      ed0a[r] += __shfl_xor(ed0a[r], off);
      ed1a[r] += __shfl_xor(ed1a[r], off);
    }
  }
  if (n16 == 0){
    #pragma unroll
    for (int r = 0; r < 4; ++r){
      int row = rowbase + q*4 + r;
      if (row < NNODES){
        atomicAdd(&esrc[row*2+0], es0[r]);
        atomicAdd(&esrc[row*2+1], es1[r]);
        atomicAdd(&edst[row*2+0], ed0a[r]);
        atomicAdd(&edst[row*2+1], ed1a[r]);
      }
    }
  }
  // zero-fill cols >= CH so the attn dwordx4 gather reads clean zeros
  #pragma unroll
  for (int r = 0; r < 4; ++r){
    int row = rowbase + q * 4 + r;
    if (row >= NNODES) continue;
    int col = bn + n16;
    __hip_bfloat16* cb = Cb + (size_t)row * HPAD + col;
    cb[0]  = __float2bfloat16(col      < CH ? ac0[r] : 0.f);
    cb[16] = __float2bfloat16(col + 16 < CH ? ac1[r] : 0.f);
    cb[32] = __float2bfloat16(col + 32 < CH ? ac2[r] : 0.f);
    cb[48] = __float2bfloat16(col + 48 < CH ? ac3[r] : 0.f);
  }
}

// ---- 4-deep batched gather: half-wave owns even/odd edges; explicit load/use split ----
// 4 uint4 loads issued back-to-back (16 VGPR) before any FMA -> forced 4 in flight
// within a 64-VGPR budget, so occupancy stays at (…,8). All indices static after
// unroll (rule #20 safe).
#define GATHER4(SS, SX) \
  for (int it = half; it < deg; it += 8){ \
    uint4 dv[4]; float a0v[4], a1v[4]; \
    _Pragma("unroll") \
    for (int u = 0; u < 4; ++u){ \
      int ii = it + 2*u; \
      bool vld = ii < deg; \
      int jj = vld ? ii : 0; \
      int s = SS[jj]; \
      float2 xv = SX[jj]; \
      a0v[u] = vld ? xv.x : 0.f; \
      a1v[u] = vld ? xv.y : 0.f; \
      dv[u] = *(const uint4*)(hrow + (size_t)s * HPAD); \
    } \
    _Pragma("unroll") \
    for (int u = 0; u < 4; ++u){ \
      float a0 = a0v[u], a1 = a1v[u]; \
      acc[0] += (0 < n0 ? a0 : a1) * bflo(dv[u].x); \
      acc[1] += (1 < n0 ? a0 : a1) * bfhi(dv[u].x); \
      acc[2] += (2 < n0 ? a0 : a1) * bflo(dv[u].y); \
      acc[3] += (3 < n0 ? a0 : a1) * bfhi(dv[u].y); \
      acc[4] += (4 < n0 ? a0 : a1) * bflo(dv[u].z); \
      acc[5] += (5 < n0 ? a0 : a1) * bfhi(dv[u].z); \
      acc[6] += (6 < n0 ? a0 : a1) * bflo(dv[u].w); \
      acc[7] += (7 < n0 ? a0 : a1) * bfhi(dv[u].w); \
    } \
  }

// ---------------- fused: attn(layer L-1) -> LDS tile -> GEMM(W_L) + scores ------------
// Block = 16 nodes, 16 waves (wave = node). Attn output never round-trips to global.
__global__ __launch_bounds__(1024, 8) void k_fused(
    const __hip_bfloat16* __restrict__ hcur,
    const float* __restrict__ esrc, const float* __restrict__ edst,
    const int* __restrict__ degv, const unsigned short* __restrict__ bucket,
    const float* __restrict__ bias,            // layer L-1 attn bias
    const __hip_bfloat16* __restrict__ Wt,     // layer L weights (tiled)
    const float* __restrict__ asrc, const float* __restrict__ adst, // layer L
    __hip_bfloat16* __restrict__ hnext,
    float* __restrict__ esN, float* __restrict__ edN){
  int w = threadIdx.x >> 6, lane = threadIdx.x & 63;
  int nodebase = blockIdx.x * 16;
  int node = nodebase + w;                      // 625 * 16 == NNODES exactly
  __shared__ unsigned short s_src[16][DCAPW];   // 4 KB
  __shared__ float2 s_x[16][DCAPW];             // 16 KB
  __shared__ short  h_lds[16][APAD];            // 8.25 KB  (A-tile, bf16 bits)
  __shared__ float  esp[16][16][2];             // 2 KB
  __shared__ float  edp[16][16][2];             // 2 KB
  // ---------- attn phase (wave-private until tile done) ----------
  int deg = degv[node]; if (deg > ECAP) deg = ECAP;
  const unsigned short* __restrict__ eb = bucket + (size_t)node * ECAP;
  float ed0 = edst[node*2+0], ed1 = edst[node*2+1];
  float sm0 = 0.f, sm1 = 0.f;
  for (int i = lane; i < deg; i += 64){
    int src = eb[i];
    float2 ev = *(const float2*)(esrc + (size_t)src * 2);
    float e0 = ev.x + ed0; e0 = e0 > 0.f ? e0 : 0.2f*e0;
    float e1 = ev.y + ed1; e1 = e1 > 0.f ? e1 : 0.2f*e1;
    float x0 = __expf(e0), x1 = __expf(e1);
    s_src[w][i] = (unsigned short)src; s_x[w][i] = make_float2(x0, x1);
    sm0 += x0; sm1 += x1;
  }
  #pragma unroll
  for (int off = 32; off > 0; off >>= 1){
    sm0 += __shfl_xor(sm0, off);
    sm1 += __shfl_xor(sm1, off);
  }
  float inv0 = 1.f / (sm0 + 1e-16f);
  float inv1 = 1.f / (sm1 + 1e-16f);
  int half = lane >> 5, hl = lane & 31;
  int c0 = hl * 8;
  int n0 = HOUT - c0; n0 = n0 < 0 ? 0 : (n0 > 8 ? 8 : n0);
  const __hip_bfloat16* __restrict__ hrow = hcur + c0;
  float acc[8] = {0.f,0.f,0.f,0.f,0.f,0.f,0.f,0.f};
  GATHER4(s_src[w], s_x[w])
  #pragma unroll
  for (int j = 0; j < 8; ++j) acc[j] += __shfl_xor(acc[j], 32);
  if (half == 0){
    if (hl < 31){
      float4 bA = *(const float4*)&bias[c0];
      float4 bB = *(const float4*)&bias[c0 + 4];
      float v0 = acc[0]*(0 < n0 ? inv0 : inv1) + bA.x;
      float v1 = acc[1]*(1 < n0 ? inv0 : inv1) + bA.y;
      float v2 = acc[2]*(2 < n0 ? inv0 : inv1) + bA.z;
      float v3 = acc[3]*(3 < n0 ? inv0 : inv1) + bA.w;
      float v4 = acc[4]*(4 < n0 ? inv0 : inv1) + bB.x;
      float v5 = acc[5]*(5 < n0 ? inv0 : inv1) + bB.y;
      float v6 = acc[6]*(6 < n0 ? inv0 : inv1) + bB.z;
      float v7 = acc[7]*(7 < n0 ? inv0 : inv1) + bB.w;
      v0 = v0 > 0.f ? v0 : 0.f; v1 = v1 > 0.f ? v1 : 0.f;
      v2 = v2 > 0.f ? v2 : 0.f; v3 = v3 > 0.f ? v3 : 0.f;
      v4 = v4 > 0.f ? v4 : 0.f; v5 = v5 > 0.f ? v5 : 0.f;
      v6 = v6 > 0.f ? v6 : 0.f; v7 = v7 > 0.f ? v7 : 0.f;
      uint4 o;
      o.x = (unsigned int)f2bfbits(v0) | ((unsigned int)f2bfbits(v1) << 16);
      o.y = (unsigned int)f2bfbits(v2) | ((unsigned int)f2bfbits(v3) << 16);
      o.z = (unsigned int)f2bfbits(v4) | ((unsigned int)f2bfbits(v5) << 16);
      o.w = (unsigned int)f2bfbits(v6) | ((unsigned int)f2bfbits(v7) << 16);
      *(uint4*)&h_lds[w][hl*8] = o;
    } else {
      float v0 = acc[0]*inv1 + bias[248];      // cols 248,249 are head-1
      float v1 = acc[1]*inv1 + bias[249];
      v0 = v0 > 0.f ? v0 : 0.f; v1 = v1 > 0.f ? v1 : 0.f;
      uint4 o;                                  // zero cols 250..255 (NaN x 0 hazard)
      o.x = (unsigned int)f2bfbits(v0) | ((unsigned int)f2bfbits(v1) << 16);
      o.y = 0u; o.z = 0u; o.w = 0u;
      *(uint4*)&h_lds[w][248] = o;
    }
  }
  __syncthreads();
  // ---------- GEMM phase: wave w owns col-tile w (cols w*16 .. w*16+15) ----------
  int n16 = lane & 15, q = lane >> 4;
  const int KC = KP1 >> 5;                       // 8
  const __hip_bfloat16* bp = Wt + ((size_t)w * KC * 16 + n16) * 32 + q * 8;
  const short* ap = &h_lds[n16][q * 8];
  f32x4 ac = {0.f,0.f,0.f,0.f};
  #pragma unroll
  for (int kc = 0; kc < KC; ++kc){
    bf16x8 av = *(const bf16x8*)(ap + kc * 32);
    bf16x8 bv = *(const bf16x8*)(bp + (size_t)kc * 512);
    ac = __builtin_amdgcn_mfma_f32_16x16x32_bf16(av, bv, ac, 0, 0, 0);
  }
  int col = w * 16 + n16;
  bool ok = col < CH;
  float av_ = ok ? asrc[col] : 0.f;
  float dv_ = ok ? adst[col] : 0.f;
  bool hh = col >= HOUT;
  float av0 = hh ? 0.f : av_, av1 = hh ? av_ : 0.f;
  float dv0 = hh ? 0.f : dv_, dv1 = hh ? dv_ : 0.f;
  float es0[4], es1[4], edd0[4], edd1[4];
  #pragma unroll
  for (int r = 0; r < 4; ++r){
    es0[r] = ac[r]*av0; es1[r] = ac[r]*av1;
    edd0[r] = ac[r]*dv0; edd1[r] = ac[r]*dv1;
  }
  #pragma unroll
  for (int off = 1; off < 16; off <<= 1){
    #pragma unroll
    for (int r = 0; r < 4; ++r){
      es0[r]  += __shfl_xor(es0[r],  off);
      es1[r]  += __shfl_xor(es1[r],  off);
      edd0[r] += __shfl_xor(edd0[r], off);
      edd1[r] += __shfl_xor(edd1[r], off);
    }
  }
  if (n16 == 0){
    #pragma unroll
    for (int r = 0; r < 4; ++r){
      esp[w][q*4+r][0] = es0[r];  esp[w][q*4+r][1] = es1[r];
      edp[w][q*4+r][0] = edd0[r]; edp[w][q*4+r][1] = edd1[r];
    }
  }
  // hnext write: zero-fill cols >= CH for next gather
  #pragma unroll
  for (int r = 0; r < 4; ++r){
    int row = nodebase + q*4 + r;
    hnext[(size_t)row * HPAD + col] = __float2bfloat16(ok ? ac[r] : 0.f);
  }
  __syncthreads();
  int t = threadIdx.x;
  if (t < 64){
    int row = t >> 2;
    int he = t & 1;
    int which = (t >> 1) & 1;
    float s = 0.f;
    #pragma unroll
    for (int w2 = 0; w2 < 16; ++w2)
      s += which ? edp[w2][row][he] : esp[w2][row][he];
    (which ? edN : esN)[(size_t)(nodebase + row) * 2 + he] = s;
  }
}

// ---------------- final softmax + gather: wave per node (feeds k_head) -----------------
__global__ __launch_bounds__(256, 8) void k_attn(const __hip_bfloat16* __restrict__ h,
                        const float* __restrict__ esrc, const float* __restrict__ edst,
                        const int* __restrict__ degv, const unsigned short* __restrict__ bucket,
                        const float* __restrict__ bias, __hip_bfloat16* __restrict__ outb){
  int wv = threadIdx.x >> 6, lane = threadIdx.x & 63;
  int node = blockIdx.x * 4 + wv;    // 2500 * 4 == NNODES exactly
  __shared__ unsigned short s_src[4][DCAPW];
  __shared__ float2 s_x[4][DCAPW];
  int deg = degv[node]; if (deg > ECAP) deg = ECAP;
  const unsigned short* __restrict__ eb = bucket + (size_t)node * ECAP;
  float ed0 = edst[node*2+0], ed1 = edst[node*2+1];
  float sm0 = 0.f, sm1 = 0.f;
  for (int i = lane; i < deg; i += 64){
    int src = eb[i];
    float2 ev = *(const float2*)(esrc + (size_t)src * 2);
    float e0 = ev.x + ed0; e0 = e0 > 0.f ? e0 : 0.2f*e0;
    float e1 = ev.y + ed1; e1 = e1 > 0.f ? e1 : 0.2f*e1;
    float x0 = __expf(e0), x1 = __expf(e1);
    s_src[wv][i] = (unsigned short)src; s_x[wv][i] = make_float2(x0, x1);
    sm0 += x0; sm1 += x1;
  }
  #pragma unroll
  for (int off = 32; off > 0; off >>= 1){
    sm0 += __shfl_xor(sm0, off);
    sm1 += __shfl_xor(sm1, off);
  }
  float inv0 = 1.f / (sm0 + 1e-16f);
  float inv1 = 1.f / (sm1 + 1e-16f);
  int half = lane >> 5, hl = lane & 31;
  int c0 = hl * 8;
  int n0 = HOUT - c0; n0 = n0 < 0 ? 0 : (n0 > 8 ? 8 : n0);
  const __hip_bfloat16* __restrict__ hrow = h + c0;
  float acc[8] = {0.f,0.f,0.f,0.f,0.f,0.f,0.f,0.f};
  GATHER4(s_src[wv], s_x[wv])
  #pragma unroll
  for (int j = 0; j < 8; ++j) acc[j] += __shfl_xor(acc[j], 32);
  if (half == 0){
    if (hl < 31){
      float4 bA = *(const float4*)&bias[c0];
      float4 bB = *(const float4*)&bias[c0 + 4];
      float v0 = acc[0]*(0 < n0 ? inv0 : inv1) + bA.x;
      float v1 = acc[1]*(1 < n0 ? inv0 : inv1) + bA.y;
      float v2 = acc[2]*(2 < n0 ? inv0 : inv1) + bA.z;
      float v3 = acc[3]*(3 < n0 ? inv0 : inv1) + bA.w;
      float v4 = acc[4]*(4 < n0 ? inv0 : inv1) + bB.x;
      float v5 = acc[5]*(5 < n0 ? inv0 : inv1) + bB.y;
      float v6 = acc[6]*(6 < n0 ? inv0 : inv1) + bB.z;
      float v7 = acc[7]*(7 < n0 ? inv0 : inv1) + bB.w;
      v0 = v0 > 0.f ? v0 : 0.f; v1 = v1 > 0.f ? v1 : 0.f;
      v2 = v2 > 0.f ? v2 : 0.f; v3 = v3 > 0.f ? v3 : 0.f;
      v4 = v4 > 0.f ? v4 : 0.f; v5 = v5 > 0.f ? v5 : 0.f;
      v6 = v6 > 0.f ? v6 : 0.f; v7 = v7 > 0.f ? v7 : 0.f;
      uint4 o;
      o.x = (unsigned int)f2bfbits(v0) | ((unsigned int)f2bfbits(v1) << 16);
      o.y = (unsigned int)f2bfbits(v2) | ((unsigned int)f2bfbits(v3) << 16);
      o.z = (unsigned int)f2bfbits(v4) | ((unsigned int)f2bfbits(v5) << 16);
      o.w = (unsigned int)f2bfbits(v6) | ((unsigned int)f2bfbits(v7) << 16);
      *(uint4*)(outb + (size_t)node * KP1 + c0) = o;
    } else {
      float v0 = acc[0]*inv1 + bias[248];
      float v1 = acc[1]*inv1 + bias[249];
      v0 = v0 > 0.f ? v0 : 0.f; v1 = v1 > 0.f ? v1 : 0.f;
      unsigned int o = (unsigned int)f2bfbits(v0) | ((unsigned int)f2bfbits(v1) << 16);
      *(unsigned int*)(outb + (size_t)node * KP1 + 248) = o;
    }
  }
}

// ---------------- fused head: segmented mean pool (bf16 input) + 4-layer MLP -----------
__global__ __launch_bounds__(256) void k_head(const __hip_bfloat16* __restrict__ xb,
                        const int* __restrict__ gstart,
                        const float* __restrict__ lw1, const float* __restrict__ lb1,
                        const float* __restrict__ lw2, const float* __restrict__ lb2,
                        const float* __restrict__ lw3, const float* __restrict__ lb3,
                        const float* __restrict__ lw4, const float* __restrict__ lb4,
                        float* __restrict__ out){
  int g = blockIdx.x;
  int tid = threadIdx.x;
  int s = gstart[g], e = gstart[g+1];
  __shared__ float gvec[256];
  __shared__ float m1[200];
  __shared__ float m2[112];
  __shared__ float m3[112];
  if (tid < 128){
    int c2 = tid * 2;
    const __hip_bfloat16* xp = xb + c2;
    float a0=0.f,a1=0.f,b0=0.f,b1=0.f;
    int n = s;
    for (; n + 3 < e; n += 4){
      unsigned int u0 = *(const unsigned int*)(xp + (size_t)n     * KP1);
      unsigned int u1 = *(const unsigned int*)(xp + (size_t)(n+1) * KP1);
      unsigned int u2 = *(const unsigned int*)(xp + (size_t)(n+2) * KP1);
      unsigned int u3 = *(const unsigned int*)(xp + (size_t)(n+3) * KP1);
      a0 += bflo(u0) + bflo(u2); a1 += bfhi(u0) + bfhi(u2);
      b0 += bflo(u1) + bflo(u3); b1 += bfhi(u1) + bfhi(u3);
    }
    for (; n < e; ++n){
      unsigned int u0 = *(const unsigned int*)(xp + (size_t)n * KP1);
      a0 += bflo(u0); a1 += bfhi(u0);
    }
    float scale = 1.f / fmaxf((float)(e - s), 1.f);
    gvec[c2]     = (a0 + b0) * scale;
    gvec[c2 + 1] = (a1 + b1) * scale;
  }
  __syncthreads();
  if (tid < 200){
    float a0=0.f,a1=0.f,a2=0.f,a3=0.f;
    int k = 0;
    for (; k + 3 < CH; k += 4){
      a0 += gvec[k]   * lw1[(size_t)k     * 200 + tid];
      a1 += gvec[k+1] * lw1[(size_t)(k+1) * 200 + tid];
      a2 += gvec[k+2] * lw1[(size_t)(k+2) * 200 + tid];
      a3 += gvec[k+3] * lw1[(size_t)(k+3) * 200 + tid];
    }
    for (; k < CH; ++k) a0 += gvec[k] * lw1[(size_t)k * 200 + tid];
    float v = a0 + a1 + a2 + a3 + lb1[tid];
    m1[tid] = v > 0.f ? v : 0.f;
  }
  __syncthreads();
  if (tid < 100){
    float a0=0.f,a1=0.f,a2=0.f,a3=0.f;
    for (int k = 0; k + 3 < 200; k += 4){
      a0 += m1[k]   * lw2[(size_t)k     * 100 + tid];
      a1 += m1[k+1] * lw2[(size_t)(k+1) * 100 + tid];
      a2 += m1[k+2] * lw2[(size_t)(k+2) * 100 + tid];
      a3 += m1[k+3] * lw2[(size_t)(k+3) * 100 + tid];
    }
    float v = a0 + a1 + a2 + a3 + lb2[tid];
    m2[tid] = v > 0.f ? v : 0.f;
  }
  __syncthreads();
  if (tid < 100){
    float a0=0.f,a1=0.f,a2=0.f,a3=0.f;
    for (int k = 0; k + 3 < 100; k += 4){
      a0 += m2[k]   * lw3[(size_t)k     * 100 + tid];
      a1 += m2[k+1] * lw3[(size_t)(k+1) * 100 + tid];
      a2 += m2[k+2] * lw3[(size_t)(k+2) * 100 + tid];
      a3 += m2[k+3] * lw3[(size_t)(k+3) * 100 + tid];
    }
    float v = a0 + a1 + a2 + a3 + lb3[tid];
    m3[tid] = v > 0.f ? v : 0.f;
  }
  __syncthreads();
  if (tid < 29){
    float a0=0.f,a1=0.f,a2=0.f,a3=0.f;
    for (int k = 0; k + 3 < 100; k += 4){
      a0 += m3[k]   * lw4[(size_t)k     * 29 + tid];
      a1 += m3[k+1] * lw4[(size_t)(k+1) * 29 + tid];
      a2 += m3[k+2] * lw4[(size_t)(k+2) * 29 + tid];
      a3 += m3[k+3] * lw4[(size_t)(k+3) * 29 + tid];
    }
    out[(size_t)g * 29 + tid] = a0 + a1 + a2 + a3 + lb4[tid];
  }
}

// ---------------- launch ----------------
extern "C" void kernel_launch(void* const* d_in, const int* in_sizes, int n_in,
                              void* d_out, int out_size, void* d_ws, size_t ws_size,
                              hipStream_t stream){
  char* ws = (char*)d_ws;
  size_t off = 0;
  auto alloc = [&](size_t bytes)->void*{
    void* p = ws + off;
    off = (off + bytes + 255) & ~(size_t)255;
    return p;
  };
  __hip_bfloat16* hb16A = (__hip_bfloat16*)alloc((size_t)NNODES * HPAD * 2);
  __hip_bfloat16* hb16B = (__hip_bfloat16*)alloc((size_t)NNODES * HPAD * 2);
  __hip_bfloat16* Abf0 = (__hip_bfloat16*)alloc((size_t)MPAD * KP0 * 2);
  __hip_bfloat16* Abf  = (__hip_bfloat16*)alloc((size_t)MPAD * KP1 * 2);
  __hip_bfloat16* Wt0  = (__hip_bfloat16*)alloc((size_t)16 * KP0 * 16 * 2);
  __hip_bfloat16* Wt1  = (__hip_bfloat16*)alloc((size_t)16 * KP1 * 16 * 2);
  __hip_bfloat16* Wt2  = (__hip_bfloat16*)alloc((size_t)16 * KP1 * 16 * 2);
  __hip_bfloat16* Wt3  = (__hip_bfloat16*)alloc((size_t)16 * KP1 * 16 * 2);
  size_t zbeg = off;
  int*   cursor = (int*)  alloc((size_t)NNODES * 4);      // doubles as deg
  float* esA  = (float*)alloc((size_t)NNODES * 2 * 4);    // layer-0 scores need zeroing
  float* edA  = (float*)alloc((size_t)NNODES * 2 * 4);
  size_t zend = off;
  float* esB  = (float*)alloc((size_t)NNODES * 2 * 4);    // plain-store targets
  float* edB  = (float*)alloc((size_t)NNODES * 2 * 4);
  unsigned short* bucket = (unsigned short*)alloc((size_t)NNODES * ECAP * 2);
  int*   gstart = (int*)alloc((size_t)(NGRAPH + 1) * 4);

  hipMemsetAsync(ws + zbeg, 0, zend - zbeg, stream);

  Args a;
  a.x = (const float*)d_in[0];
  a.eidx = (const int*)d_in[1];
  a.batch = (const int*)d_in[2];
  a.W0 = (const float*)d_in[3];  a.W1 = (const float*)d_in[7];
  a.W2 = (const float*)d_in[11]; a.W3 = (const float*)d_in[15];
  a.Abf0 = Abf0;
  a.Wt0 = Wt0; a.Wt1 = Wt1; a.Wt2 = Wt2; a.Wt3 = Wt3;
  a.cursor = cursor; a.bucket = bucket; a.gstart = gstart;

  k_pre<<<(ETOT + 255)/256, 256, 0, stream>>>(a);

  k_gemm<<<dim3(NTILE, 4), 256, 0, stream>>>(Abf0, Wt0, hb16A,
      (const float*)d_in[4], (const float*)d_in[5], esA, edA, KP0);

  k_fused<<<NNODES/16, 1024, 0, stream>>>(hb16A, esA, edA, cursor, bucket,
      (const float*)d_in[6],  Wt1, (const float*)d_in[8],  (const float*)d_in[9],
      hb16B, esB, edB);
  k_fused<<<NNODES/16, 1024, 0, stream>>>(hb16B, esB, edB, cursor, bucket,
      (const float*)d_in[10], Wt2, (const float*)d_in[12], (const float*)d_in[13],
      hb16A, esA, edA);
  k_fused<<<NNODES/16, 1024, 0, stream>>>(hb16A, esA, edA, cursor, bucket,
      (const float*)d_in[14], Wt3, (const float*)d_in[16], (const float*)d_in[17],
      hb16B, esB, edB);

  k_attn<<<NNODES/4, 256, 0, stream>>>(hb16B, esB, edB, cursor, bucket,
      (const float*)d_in[18], Abf);

  k_head<<<NGRAPH, 256, 0, stream>>>(Abf, gstart,
      (const float*)d_in[19], (const float*)d_in[20],
      (const float*)d_in[21], (const float*)d_in[22],
      (const float*)d_in[23], (const float*)d_in[24],
      (const float*)d_in[25], (const float*)d_in[26],
      (float*)d_out);
}